// Round 5
// baseline (414.467 us; speedup 1.0000x reference)
//
#include <hip/hip_runtime.h>
#include <hip/hip_cooperative_groups.h>
#include <math.h>

namespace cg = cooperative_groups;

#define S_ 4
#define C_ 384
#define H_ 96
#define W_ 96
#define B_ 8
#define M_ 64
#define HW_ (H_ * W_)
#define EPSV 1e-6f
#define BETA_V 0.3f
#define TEMP_V 0.07f

#define NB_A (S_ * C_)        // 1536 plane-sum units
#define NB_B (M_ * (C_ / 4))  // 6144 window units
#define NB_PREP (NB_A + NB_B + 1)
#define NB_SCORE (B_ * HW_ / 64)  // 1152 score units
#define GRID_ 1024            // <= 4 blocks/CU * 256 CU guaranteed by launch_bounds(256,4)

__device__ __forceinline__ float wave_sum(float v) {
#pragma unroll
    for (int o = 32; o; o >>= 1) v += __shfl_down(v, o, 64);
    return v;
}

__device__ __forceinline__ float block_sum(float v) {
    __shared__ float sm[4];
    int lane = threadIdx.x & 63;
    int wid = threadIdx.x >> 6;
    v = wave_sum(v);
    if (lane == 0) sm[wid] = v;
    __syncthreads();
    float r = sm[0] + sm[1] + sm[2] + sm[3];
    __syncthreads();
    return r;
}

// ---------------- device helpers shared by fused and split paths ----------------

__device__ __forceinline__ void do_plane_unit(int unit, const float* __restrict__ feats,
                                              const int* __restrict__ mask,
                                              float* __restrict__ partial) {
    int t = threadIdx.x;
    int s = unit / C_;
    const float4* fp = (const float4*)(feats + (size_t)unit * HW_);
    const int4* mp = (const int4*)(mask + (size_t)s * HW_);
    float acc = 0.0f;
    for (int i = t; i < HW_ / 4; i += 256) {
        float4 f = fp[i];
        int4 m = mp[i];
        acc += f.x * (float)m.x + f.y * (float)m.y + f.z * (float)m.z + f.w * (float)m.w;
    }
    float tot = block_sum(acc);
    if (t == 0) partial[unit] = tot;
}

__device__ __forceinline__ void do_window_unit(int bidb, float* smem,
                                               const float* __restrict__ feats,
                                               const int* __restrict__ mask,
                                               const int* __restrict__ pos,
                                               const int* __restrict__ samp,
                                               const int* __restrict__ rad,
                                               float* __restrict__ proto,
                                               float* __restrict__ msum_out) {
    int t = threadIdx.x;
    const int CG = C_ / 4;  // 96
    int m = bidb / CG;
    int cgi = bidb % CG;
    int y = pos[2 * m + 0];
    int x = pos[2 * m + 1];
    int s = samp[m];
    int ri = rad[m];
    int r = (ri == 0) ? 4 : (ri == 1) ? 8 : 16;
    int y0 = max(y - r, 0), y1 = min(y + r + 1, H_);
    int x0 = max(x - r, 0), x1 = min(x + r + 1, W_);
    int ww = x1 - x0;
    int n = (y1 - y0) * ww;

    const int* mp = mask + (size_t)s * HW_;
    float macc = 0.0f;
    {
        int yy = t / ww;
        int xx = t - yy * ww;
        int dy = 256 / ww, dx = 256 - dy * ww;  // dx < ww
        for (int i = t; i < n; i += 256) {
            float mv = (float)mp[(y0 + yy) * W_ + x0 + xx];
            smem[i] = mv;
            macc += mv;
            xx += dx; yy += dy;
            if (xx >= ww) { xx -= ww; ++yy; }
        }
    }
    float msumv = block_sum(macc);  // internal barrier publishes smem
    if (cgi == 0 && t == 0) msum_out[m] = msumv;
    float inv = 1.0f / (msumv + EPSV);

    int wid = t >> 6;
    int lane = t & 63;
    int c = cgi * 4 + wid;
    const float* fp = feats + ((size_t)s * C_ + c) * HW_;
    float acc = 0.0f;
    {
        int yy = lane / ww;
        int xx = lane - yy * ww;
        int dy = 64 / ww, dx = 64 - dy * ww;
        for (int i = lane; i < n; i += 64) {
            acc += fp[(y0 + yy) * W_ + x0 + xx] * smem[i];
            xx += dx; yy += dy;
            if (xx >= ww) { xx -= ww; ++yy; }
        }
    }
    acc = wave_sum(acc);
    if (lane == 0) proto[m * C_ + c] = acc * inv;
    __syncthreads();  // protect smem before reuse
}

__device__ __forceinline__ void do_fg_unit(const int* __restrict__ mask,
                                           float* __restrict__ fgp) {
    int t = threadIdx.x;
    const int4* mp4 = (const int4*)mask;
    float acc = 0.0f;
    for (int i = t; i < S_ * HW_ / 4; i += 256) {
        int4 m = mp4[i];
        acc += (float)(m.x + m.y + m.z + m.w);
    }
    float fg = block_sum(acc);
    if (t == 0) fgp[0] = fg;
}

__device__ __forceinline__ void do_finalize(float* smem,
                                            const float* __restrict__ partial,
                                            const float* __restrict__ msum,
                                            const float* __restrict__ proto,
                                            const float* __restrict__ fgp,
                                            float* __restrict__ v) {
    int t = threadIdx.x;
    int wid = t >> 6;
    int lane = t & 63;
    float* gv = smem;            // 384
    float* pn = smem + C_;       // 64
    float* wq = smem + C_ + M_;  // 64

    float invfg = 1.0f / (fgp[0] + EPSV);
    for (int c = t; c < C_; c += 256) {
        float tv = 0.0f;
        for (int s = 0; s < S_; ++s) tv += partial[s * C_ + c];
        gv[c] = tv * invfg;
    }
    __syncthreads();

    float sq = 0.0f;
    for (int c = t; c < C_; c += 256) sq += gv[c] * gv[c];
    float gn = block_sum(sq);
    gn = fmaxf(sqrtf(gn), 1e-12f);

    float wa = (t < M_) ? msum[t] : 0.0f;
    float T = block_sum(wa);
    float wb = (t < M_) ? msum[t] / (T + EPSV) : 0.0f;
    float wsum = block_sum(wb);

    for (int m = wid; m < M_; m += 4) {
        float a = 0.0f;
        for (int c2 = lane; c2 < C_; c2 += 64) {
            float p = proto[m * C_ + c2];
            a += p * p;
        }
        a = wave_sum(a);
        if (lane == 0) pn[m] = fmaxf(sqrtf(a), 1e-12f);
    }
    __syncthreads();

    if (t < M_) {
        float w = (msum[t] / (T + EPSV)) / (wsum + EPSV);
        wq[t] = w / pn[t];
    }
    __syncthreads();

    for (int c = t; c < C_; c += 256) {
        float vl = 0.0f;
        for (int m = 0; m < M_; ++m) vl += wq[m] * proto[m * C_ + c];
        v[c] = BETA_V * (gv[c] / gn) + (1.0f - BETA_V) * vl;
    }
}

__device__ __forceinline__ void do_score_unit(int unit, const float* vs, float* sd, float* ss,
                                              const float* __restrict__ q,
                                              float* __restrict__ out) {
    int t = threadIdx.x;
    int wid = t >> 6;
    int lane = t & 63;
    int b = unit / (HW_ / 64);
    int p0 = (unit - b * (HW_ / 64)) * 64;
    const float* qp = q + ((size_t)b * C_ + wid * 96) * HW_ + p0 + lane;

    float dot = 0.0f, sq = 0.0f;
#pragma unroll 8
    for (int c = 0; c < 96; ++c) {
        float val = qp[(size_t)c * HW_];
        dot += val * vs[wid * 96 + c];
        sq += val * val;
    }
    sd[wid * 64 + lane] = dot;
    ss[wid * 64 + lane] = sq;
    __syncthreads();
    if (wid == 0) {
        float d = sd[lane] + sd[64 + lane] + sd[128 + lane] + sd[192 + lane];
        float s2 = ss[lane] + ss[64 + lane] + ss[128 + lane] + ss[192 + lane];
        float sv = d / fmaxf(sqrtf(s2), 1e-12f);
        float o = sv / TEMP_V;
        float* ob = out + (size_t)b * 2 * HW_;
        ob[p0 + lane] = -o;
        ob[HW_ + p0 + lane] = o;
    }
    __syncthreads();  // protect sd/ss before next unit
}

// ---------------- fused cooperative kernel ----------------

__global__ __launch_bounds__(256, 4) void k_fused(
    const float* __restrict__ feats, const int* __restrict__ mask,
    const int* __restrict__ pos, const int* __restrict__ samp,
    const int* __restrict__ rad, const float* __restrict__ q,
    float* __restrict__ out, float* __restrict__ partial,
    float* __restrict__ proto, float* __restrict__ msum_out,
    float* __restrict__ fgp, float* __restrict__ v) {
    cg::grid_group grid = cg::this_grid();
    __shared__ float smem[1089];

    // phase 1: prep
    for (int unit = blockIdx.x; unit < NB_PREP; unit += GRID_) {
        if (unit < NB_A) {
            do_plane_unit(unit, feats, mask, partial);
        } else if (unit < NB_A + NB_B) {
            do_window_unit(unit - NB_A, smem, feats, mask, pos, samp, rad, proto, msum_out);
        } else {
            do_fg_unit(mask, fgp);
        }
    }
    __threadfence();
    grid.sync();

    // phase 2: block 0 builds combined vector v
    if (blockIdx.x == 0) {
        do_finalize(smem, partial, msum_out, proto, fgp, v);
        __threadfence();
    }
    grid.sync();

    // phase 3: score units, grid-stride
    {
        float* vs = smem;            // 384
        float* sd = smem + C_;       // 256
        float* ss = smem + C_ + 256; // 256
        for (int c = threadIdx.x; c < C_; c += 256) vs[c] = v[c];
        __syncthreads();
        for (int unit = blockIdx.x; unit < NB_SCORE; unit += GRID_)
            do_score_unit(unit, vs, sd, ss, q, out);
    }
}

// ---------------- split-path fallback kernels (round-3 pipeline) ----------------

__global__ __launch_bounds__(256) void k_prep(const float* __restrict__ feats,
                                              const int* __restrict__ mask,
                                              const int* __restrict__ pos,
                                              const int* __restrict__ samp,
                                              const int* __restrict__ rad,
                                              float* __restrict__ partial,
                                              float* __restrict__ proto,
                                              float* __restrict__ msum_out,
                                              float* __restrict__ fgp) {
    __shared__ float smem[1089];
    int bid = blockIdx.x;
    if (bid < NB_A) do_plane_unit(bid, feats, mask, partial);
    else if (bid < NB_A + NB_B) do_window_unit(bid - NB_A, smem, feats, mask, pos, samp, rad, proto, msum_out);
    else do_fg_unit(mask, fgp);
}

__global__ __launch_bounds__(256) void k_finalize(const float* __restrict__ partial,
                                                  const float* __restrict__ msum,
                                                  const float* __restrict__ proto,
                                                  const float* __restrict__ fgp,
                                                  float* __restrict__ v) {
    __shared__ float smem[512];
    do_finalize(smem, partial, msum, proto, fgp, v);
}

__global__ __launch_bounds__(256) void k_score(const float* __restrict__ q,
                                               const float* __restrict__ v,
                                               float* __restrict__ out) {
    __shared__ float smem[896];
    float* vs = smem;
    float* sd = smem + C_;
    float* ss = smem + C_ + 256;
    for (int c = threadIdx.x; c < C_; c += 256) vs[c] = v[c];
    __syncthreads();
    do_score_unit(blockIdx.x, vs, sd, ss, q, out);
}

extern "C" void kernel_launch(void* const* d_in, const int* in_sizes, int n_in,
                              void* d_out, int out_size, void* d_ws, size_t ws_size,
                              hipStream_t stream) {
    const float* support_feats = (const float*)d_in[0];
    const int* support_masks = (const int*)d_in[1];
    const float* query_feats = (const float*)d_in[2];
    const int* anchor_pos = (const int*)d_in[3];
    const int* anchor_sample = (const int*)d_in[4];
    const int* anchor_radius = (const int*)d_in[5];
    float* out = (float*)d_out;

    float* ws = (float*)d_ws;
    float* ws_partial = ws;                 // S*C = 1536
    float* ws_msum = ws_partial + S_ * C_;  // 64
    float* ws_proto = ws_msum + M_;         // M*C = 24576
    float* ws_v = ws_proto + M_ * C_;       // 384
    float* ws_fg = ws_v + C_;               // 1

    void* args[] = {(void*)&support_feats, (void*)&support_masks, (void*)&anchor_pos,
                    (void*)&anchor_sample, (void*)&anchor_radius, (void*)&query_feats,
                    (void*)&out, (void*)&ws_partial, (void*)&ws_proto, (void*)&ws_msum,
                    (void*)&ws_fg, (void*)&ws_v};
    hipError_t err = hipLaunchCooperativeKernel((const void*)k_fused, dim3(GRID_),
                                                dim3(256), args, 0, stream);
    if (err != hipSuccess) {
        // fallback: proven 3-kernel pipeline
        k_prep<<<NB_PREP, 256, 0, stream>>>(support_feats, support_masks, anchor_pos,
                                            anchor_sample, anchor_radius,
                                            ws_partial, ws_proto, ws_msum, ws_fg);
        k_finalize<<<1, 256, 0, stream>>>(ws_partial, ws_msum, ws_proto, ws_fg, ws_v);
        k_score<<<NB_SCORE, 256, 0, stream>>>(query_feats, ws_v, out);
    }
}

// Round 6
// 154.451 us; speedup vs baseline: 2.6835x; 2.6835x over previous
//
#include <hip/hip_runtime.h>
#include <math.h>

#define S_ 4
#define C_ 384
#define H_ 96
#define W_ 96
#define B_ 8
#define M_ 64
#define HW_ (H_ * W_)
#define EPSV 1e-6f
#define BETA_V 0.3f
#define TEMP_V 0.07f

#define NB_A (S_ * C_)            // 1536 plane-sum blocks
#define NB_B (M_ * (C_ / 4))      // 6144 window blocks
#define NB_PREP (NB_A + NB_B + 1)
#define NB_SCORE (B_ * HW_ / 64)  // 1152 score units
#define REP_ 5                    // score replication for measurement

__device__ __forceinline__ float wave_sum(float v) {
#pragma unroll
    for (int o = 32; o; o >>= 1) v += __shfl_down(v, o, 64);
    return v;
}

__device__ __forceinline__ float block_sum(float v) {
    __shared__ float sm[4];
    int lane = threadIdx.x & 63;
    int wid = threadIdx.x >> 6;
    v = wave_sum(v);
    if (lane == 0) sm[wid] = v;
    __syncthreads();
    float r = sm[0] + sm[1] + sm[2] + sm[3];
    __syncthreads();
    return r;
}

// Fused prep: role A = per-(s,c) masked plane sums; role B = per-(anchor,
// channel-group) window sums; role C = fg mask total. (identical to round 3)
__global__ __launch_bounds__(256) void k_prep(const float* __restrict__ feats,
                                              const int* __restrict__ mask,
                                              const int* __restrict__ pos,
                                              const int* __restrict__ samp,
                                              const int* __restrict__ rad,
                                              float* __restrict__ partial,
                                              float* __restrict__ proto,
                                              float* __restrict__ msum_out,
                                              float* __restrict__ fg_out) {
    int bid = blockIdx.x;
    int t = threadIdx.x;

    if (bid < NB_A) {
        int s = bid / C_;
        const float4* fp = (const float4*)(feats + (size_t)bid * HW_);
        const int4* mp = (const int4*)(mask + (size_t)s * HW_);
        float acc = 0.0f;
        for (int i = t; i < HW_ / 4; i += 256) {
            float4 f = fp[i];
            int4 m = mp[i];
            acc += f.x * (float)m.x + f.y * (float)m.y + f.z * (float)m.z + f.w * (float)m.w;
        }
        float tot = block_sum(acc);
        if (t == 0) partial[bid] = tot;
        return;
    }
    bid -= NB_A;
    if (bid < NB_B) {
        const int CG = C_ / 4;  // 96
        int m = bid / CG;
        int cg = bid % CG;
        int y = pos[2 * m + 0];
        int x = pos[2 * m + 1];
        int s = samp[m];
        int ri = rad[m];
        int r = (ri == 0) ? 4 : (ri == 1) ? 8 : 16;
        int y0 = max(y - r, 0), y1 = min(y + r + 1, H_);
        int x0 = max(x - r, 0), x1 = min(x + r + 1, W_);
        int ww = x1 - x0;
        int n = (y1 - y0) * ww;

        __shared__ float mwin[33 * 33];
        const int* mp = mask + (size_t)s * HW_;
        float macc = 0.0f;
        {
            int yy = t / ww;
            int xx = t - yy * ww;
            int dy = 256 / ww, dx = 256 - dy * ww;  // dx < ww
            for (int i = t; i < n; i += 256) {
                float mv = (float)mp[(y0 + yy) * W_ + x0 + xx];
                mwin[i] = mv;
                macc += mv;
                xx += dx; yy += dy;
                if (xx >= ww) { xx -= ww; ++yy; }
            }
        }
        float msumv = block_sum(macc);  // internal barrier publishes mwin
        if (cg == 0 && t == 0) msum_out[m] = msumv;
        float inv = 1.0f / (msumv + EPSV);

        int wid = t >> 6;
        int lane = t & 63;
        int c = cg * 4 + wid;
        const float* fp = feats + ((size_t)s * C_ + c) * HW_;
        float acc = 0.0f;
        {
            int yy = lane / ww;
            int xx = lane - yy * ww;
            int dy = 64 / ww, dx = 64 - dy * ww;
            for (int i = lane; i < n; i += 64) {
                acc += fp[(y0 + yy) * W_ + x0 + xx] * mwin[i];
                xx += dx; yy += dy;
                if (xx >= ww) { xx -= ww; ++yy; }
            }
        }
        acc = wave_sum(acc);
        if (lane == 0) proto[m * C_ + c] = acc * inv;
        return;
    }
    // fg = total mask sum
    const int4* mp4 = (const int4*)mask;
    float acc = 0.0f;
    for (int i = t; i < S_ * HW_ / 4; i += 256) {
        int4 m = mp4[i];
        acc += (float)(m.x + m.y + m.z + m.w);
    }
    float fg = block_sum(acc);
    if (t == 0) fg_out[0] = fg;
}

__global__ __launch_bounds__(256) void k_finalize(const float* __restrict__ partial,
                                                  const float* __restrict__ msum,
                                                  const float* __restrict__ proto,
                                                  const float* __restrict__ fg_in,
                                                  float* __restrict__ v) {
    int tid = threadIdx.x;
    int wid = tid >> 6;
    int lane = tid & 63;

    float invfg = 1.0f / (fg_in[0] + EPSV);

    __shared__ float gv[C_];
    for (int c = tid; c < C_; c += 256) {
        float tv = 0.0f;
        for (int s = 0; s < S_; ++s) tv += partial[s * C_ + c];
        gv[c] = tv * invfg;
    }
    __syncthreads();

    float sq = 0.0f;
    for (int c = tid; c < C_; c += 256) sq += gv[c] * gv[c];
    float gn = block_sum(sq);
    gn = fmaxf(sqrtf(gn), 1e-12f);

    float wa = (tid < M_) ? msum[tid] : 0.0f;
    float T = block_sum(wa);
    float wb = (tid < M_) ? msum[tid] / (T + EPSV) : 0.0f;
    float wsum = block_sum(wb);

    __shared__ float pn[M_];
    for (int m = wid; m < M_; m += 4) {
        float a = 0.0f;
        for (int c = lane; c < C_; c += 64) {
            float p = proto[m * C_ + c];
            a += p * p;
        }
        a = wave_sum(a);
        if (lane == 0) pn[m] = fmaxf(sqrtf(a), 1e-12f);
    }
    __syncthreads();

    __shared__ float wq[M_];
    if (tid < M_) {
        float w = (msum[tid] / (T + EPSV)) / (wsum + EPSV);
        wq[tid] = w / pn[tid];
    }
    __syncthreads();

    for (int c = tid; c < C_; c += 256) {
        float vl = 0.0f;
        for (int m = 0; m < M_; ++m) vl += wq[m] * proto[m * C_ + c];
        v[c] = BETA_V * (gv[c] / gn) + (1.0f - BETA_V) * vl;
    }
}

// Score with REP_-fold replication in ONE dispatch: block i handles unit
// i % NB_SCORE. Duplicate blocks write identical values (benign, deterministic).
// Purpose: single score dispatch > 64 us -> visible in rocprof top-5 with its
// own counters; per-unit code identical to round 3's k_score.
__global__ __launch_bounds__(256) void k_score_rep(const float* __restrict__ q,
                                                   const float* __restrict__ v,
                                                   float* __restrict__ out) {
    __shared__ float vs[C_];
    __shared__ float sd[256];
    __shared__ float ss[256];
    for (int c = threadIdx.x; c < C_; c += 256) vs[c] = v[c];
    __syncthreads();

    int unit = blockIdx.x;
    unit -= (unit / NB_SCORE) * NB_SCORE;

    int t = threadIdx.x;
    int wid = t >> 6;
    int lane = t & 63;
    int b = unit / (HW_ / 64);
    int p0 = (unit - b * (HW_ / 64)) * 64;
    const float* qp = q + ((size_t)b * C_ + wid * 96) * HW_ + p0 + lane;

    float dot = 0.0f, sq = 0.0f;
#pragma unroll 8
    for (int c = 0; c < 96; ++c) {
        float val = qp[(size_t)c * HW_];
        dot += val * vs[wid * 96 + c];
        sq += val * val;
    }
    sd[wid * 64 + lane] = dot;
    ss[wid * 64 + lane] = sq;
    __syncthreads();
    if (wid == 0) {
        float d = sd[lane] + sd[64 + lane] + sd[128 + lane] + sd[192 + lane];
        float s2 = ss[lane] + ss[64 + lane] + ss[128 + lane] + ss[192 + lane];
        float sv = d / fmaxf(sqrtf(s2), 1e-12f);
        float o = sv / TEMP_V;
        float* ob = out + (size_t)b * 2 * HW_;
        ob[p0 + lane] = -o;
        ob[HW_ + p0 + lane] = o;
    }
}

extern "C" void kernel_launch(void* const* d_in, const int* in_sizes, int n_in,
                              void* d_out, int out_size, void* d_ws, size_t ws_size,
                              hipStream_t stream) {
    const float* support_feats = (const float*)d_in[0];
    const int* support_masks = (const int*)d_in[1];
    const float* query_feats = (const float*)d_in[2];
    const int* anchor_pos = (const int*)d_in[3];
    const int* anchor_sample = (const int*)d_in[4];
    const int* anchor_radius = (const int*)d_in[5];
    float* out = (float*)d_out;

    float* ws = (float*)d_ws;
    float* ws_partial = ws;                 // S*C = 1536
    float* ws_msum = ws_partial + S_ * C_;  // 64
    float* ws_proto = ws_msum + M_;         // M*C = 24576
    float* ws_v = ws_proto + M_ * C_;       // 384
    float* ws_fg = ws_v + C_;               // 1

    k_prep<<<NB_PREP, 256, 0, stream>>>(support_feats, support_masks, anchor_pos,
                                        anchor_sample, anchor_radius,
                                        ws_partial, ws_proto, ws_msum, ws_fg);
    k_finalize<<<1, 256, 0, stream>>>(ws_partial, ws_msum, ws_proto, ws_fg, ws_v);
    k_score_rep<<<REP_ * NB_SCORE, 256, 0, stream>>>(query_feats, ws_v, out);
}

// Round 7
// 103.740 us; speedup vs baseline: 3.9952x; 1.4888x over previous
//
#include <hip/hip_runtime.h>
#include <math.h>

#define S_ 4
#define C_ 384
#define H_ 96
#define W_ 96
#define B_ 8
#define M_ 64
#define HW_ (H_ * W_)
#define EPSV 1e-6f
#define BETA_V 0.3f
#define TEMP_V 0.07f

#define NB_A (S_ * C_)            // 1536 plane-sum blocks
#define CGB 64                    // channels per role-B block
#define NB_B (M_ * (C_ / CGB))    // 384 window blocks
#define NB_PREP (NB_A + NB_B + 1)

#define NSLICE 4                  // channel slices for score S1
#define CS (C_ / NSLICE)          // 96 channels per slice
#define NTILE (HW_ / 256)         // 36 pixel tiles per image
#define NB_S1 (B_ * NSLICE * NTILE)  // 1152
#define NB_S2 (B_ * HW_ / 256)       // 288

__device__ __forceinline__ float wave_sum(float v) {
#pragma unroll
    for (int o = 32; o; o >>= 1) v += __shfl_down(v, o, 64);
    return v;
}

__device__ __forceinline__ float block_sum(float v) {
    __shared__ float sm[4];
    int lane = threadIdx.x & 63;
    int wid = threadIdx.x >> 6;
    v = wave_sum(v);
    if (lane == 0) sm[wid] = v;
    __syncthreads();
    float r = sm[0] + sm[1] + sm[2] + sm[3];
    __syncthreads();
    return r;
}

// Fused prep: role A = per-(s,c) masked plane sums (1536 blocks);
// role B = per-(anchor, 64-channel group) window sums (384 blocks);
// role C = fg mask total (1 block).
__global__ __launch_bounds__(256) void k_prep(const float* __restrict__ feats,
                                              const int* __restrict__ mask,
                                              const int* __restrict__ pos,
                                              const int* __restrict__ samp,
                                              const int* __restrict__ rad,
                                              float* __restrict__ partial,
                                              float* __restrict__ proto,
                                              float* __restrict__ msum_out,
                                              float* __restrict__ fg_out) {
    int bid = blockIdx.x;
    int t = threadIdx.x;

    if (bid < NB_A) {
        // ---- role A: partial[sc] = sum_p feats[s,c,p] * mask[s,p]
        int s = bid / C_;
        const float4* fp = (const float4*)(feats + (size_t)bid * HW_);
        const int4* mp = (const int4*)(mask + (size_t)s * HW_);
        float acc = 0.0f;
#pragma unroll
        for (int k = 0; k < HW_ / 4 / 256; ++k) {  // exactly 9 iterations
            int i = t + k * 256;
            float4 f = fp[i];
            int4 m = mp[i];
            acc += f.x * (float)m.x + f.y * (float)m.y + f.z * (float)m.z + f.w * (float)m.w;
        }
        float tot = block_sum(acc);
        if (t == 0) partial[bid] = tot;
        return;
    }
    bid -= NB_A;
    if (bid < NB_B) {
        // ---- role B: one block per (anchor m, 64-channel group cg)
        const int NCG = C_ / CGB;  // 6
        int m = bid / NCG;
        int cg = bid % NCG;
        int y = pos[2 * m + 0];
        int x = pos[2 * m + 1];
        int s = samp[m];
        int ri = rad[m];
        int r = (ri == 0) ? 4 : (ri == 1) ? 8 : 16;
        int y0 = max(y - r, 0), y1 = min(y + r + 1, H_);
        int x0 = max(x - r, 0), x1 = min(x + r + 1, W_);
        int ww = x1 - x0;
        int n = (y1 - y0) * ww;

        __shared__ float mwin[33 * 33];
        const int* mp = mask + (size_t)s * HW_;
        float macc = 0.0f;
        {
            int yy = t / ww;
            int xx = t - yy * ww;
            int dy = 256 / ww, dx = 256 - dy * ww;  // dx < ww
            for (int i = t; i < n; i += 256) {
                float mv = (float)mp[(y0 + yy) * W_ + x0 + xx];
                mwin[i] = mv;
                macc += mv;
                xx += dx; yy += dy;
                if (xx >= ww) { xx -= ww; ++yy; }
            }
        }
        float msumv = block_sum(macc);  // internal barrier publishes mwin
        if (cg == 0 && t == 0) msum_out[m] = msumv;
        float inv = 1.0f / (msumv + EPSV);

        int wid = t >> 6;
        int lane = t & 63;
        // wave handles 16 channels, processed in 4 batches of 4 (4x load MLP)
        int cbase = cg * CGB + wid * 16;
        const float* fbase = feats + (size_t)s * C_ * HW_;
        for (int jb = 0; jb < 4; ++jb) {
            int c0 = cbase + jb * 4;
            const float* f0 = fbase + (size_t)(c0 + 0) * HW_;
            const float* f1 = fbase + (size_t)(c0 + 1) * HW_;
            const float* f2 = fbase + (size_t)(c0 + 2) * HW_;
            const float* f3 = fbase + (size_t)(c0 + 3) * HW_;
            float a0 = 0.f, a1 = 0.f, a2 = 0.f, a3 = 0.f;
            int yy = lane / ww;
            int xx = lane - yy * ww;
            int dy = 64 / ww, dx = 64 - dy * ww;
            for (int i = lane; i < n; i += 64) {
                int off = (y0 + yy) * W_ + x0 + xx;
                float mv = mwin[i];
                a0 += f0[off] * mv;
                a1 += f1[off] * mv;
                a2 += f2[off] * mv;
                a3 += f3[off] * mv;
                xx += dx; yy += dy;
                if (xx >= ww) { xx -= ww; ++yy; }
            }
            a0 = wave_sum(a0);
            a1 = wave_sum(a1);
            a2 = wave_sum(a2);
            a3 = wave_sum(a3);
            if (lane == 0) {
                proto[m * C_ + c0 + 0] = a0 * inv;
                proto[m * C_ + c0 + 1] = a1 * inv;
                proto[m * C_ + c0 + 2] = a2 * inv;
                proto[m * C_ + c0 + 3] = a3 * inv;
            }
        }
        return;
    }
    // ---- role C: fg = total mask sum
    const int4* mp4 = (const int4*)mask;
    float acc = 0.0f;
    for (int i = t; i < S_ * HW_ / 4; i += 256) {
        int4 m = mp4[i];
        acc += (float)(m.x + m.y + m.z + m.w);
    }
    float fg = block_sum(acc);
    if (t == 0) fg_out[0] = fg;
}

// Single block: combine into the final C-vector v. All inputs L2-resident.
__global__ __launch_bounds__(256) void k_finalize(const float* __restrict__ partial,
                                                  const float* __restrict__ msum,
                                                  const float* __restrict__ proto,
                                                  const float* __restrict__ fg_in,
                                                  float* __restrict__ v) {
    int tid = threadIdx.x;
    int wid = tid >> 6;
    int lane = tid & 63;

    float invfg = 1.0f / (fg_in[0] + EPSV);

    __shared__ float gv[C_];
    for (int c = tid; c < C_; c += 256) {
        float tv = 0.0f;
        for (int s = 0; s < S_; ++s) tv += partial[s * C_ + c];
        gv[c] = tv * invfg;
    }
    __syncthreads();

    float sq = 0.0f;
    for (int c = tid; c < C_; c += 256) sq += gv[c] * gv[c];
    float gn = block_sum(sq);
    gn = fmaxf(sqrtf(gn), 1e-12f);

    float wa = (tid < M_) ? msum[tid] : 0.0f;
    float T = block_sum(wa);
    float wb = (tid < M_) ? msum[tid] / (T + EPSV) : 0.0f;
    float wsum = block_sum(wb);

    __shared__ float pn[M_];
    for (int m = wid; m < M_; m += 4) {
        float a = 0.0f;
        for (int c = lane; c < C_; c += 64) {
            float p = proto[m * C_ + c];
            a += p * p;
        }
        a = wave_sum(a);
        if (lane == 0) pn[m] = fmaxf(sqrtf(a), 1e-12f);
    }
    __syncthreads();

    __shared__ float wq[M_];
    if (tid < M_) {
        float w = (msum[tid] / (T + EPSV)) / (wsum + EPSV);
        wq[tid] = w / pn[tid];
    }
    __syncthreads();

    for (int c = tid; c < C_; c += 256) {
        float vl = 0.0f;
        for (int m = 0; m < M_; ++m) vl += wq[m] * proto[m * C_ + c];
        v[c] = BETA_V * (gv[c] / gn) + (1.0f - BETA_V) * vl;
    }
}

// Score S1: block = (b, slice, tile). 256 px/tile, 96 ch/slice. Thread = 4 px
// (float4, 1 KB/wave/channel), wave = 24 channels. Cross-wave LDS reduce ->
// per-pixel partial dot/sq for this slice.
__global__ __launch_bounds__(256) void k_score1(const float* __restrict__ q,
                                                const float* __restrict__ v,
                                                float* __restrict__ wsd,
                                                float* __restrict__ wss) {
    int bid = blockIdx.x;
    int tile = bid % NTILE;
    int bs = bid / NTILE;
    int sl = bs % NSLICE;
    int b = bs / NSLICE;

    int wid = threadIdx.x >> 6;
    int lane = threadIdx.x & 63;
    int p0 = tile * 256;

    const float4* qp = (const float4*)(q + (size_t)b * C_ * HW_ + p0);
    int c0 = sl * CS + wid * 24;

    float4 dot = {0.f, 0.f, 0.f, 0.f};
    float4 sq = {0.f, 0.f, 0.f, 0.f};
#pragma unroll 8
    for (int j = 0; j < 24; ++j) {
        int c = c0 + j;
        float4 f = qp[(size_t)c * (HW_ / 4) + lane];
        float vc = v[c];
        dot.x += f.x * vc; dot.y += f.y * vc; dot.z += f.z * vc; dot.w += f.w * vc;
        sq.x += f.x * f.x; sq.y += f.y * f.y; sq.z += f.z * f.z; sq.w += f.w * f.w;
    }

    __shared__ float4 sd[4][64];
    __shared__ float4 ss[4][64];
    sd[wid][lane] = dot;
    ss[wid][lane] = sq;
    __syncthreads();
    if (wid == 0) {
        float4 d = sd[0][lane];
        float4 s2 = ss[0][lane];
#pragma unroll
        for (int w = 1; w < 4; ++w) {
            float4 a = sd[w][lane];
            float4 b2 = ss[w][lane];
            d.x += a.x; d.y += a.y; d.z += a.z; d.w += a.w;
            s2.x += b2.x; s2.y += b2.y; s2.z += b2.z; s2.w += b2.w;
        }
        size_t base = ((size_t)(b * NSLICE + sl) * HW_ + p0) / 4;
        ((float4*)wsd)[base + lane] = d;
        ((float4*)wss)[base + lane] = s2;
    }
}

// Score S2: reduce NSLICE partials per pixel, write both logit planes.
__global__ __launch_bounds__(256) void k_score2(const float* __restrict__ wsd,
                                                const float* __restrict__ wss,
                                                float* __restrict__ out) {
    int px = blockIdx.x * 256 + threadIdx.x;  // < B_*HW_
    int b = px / HW_;
    int p = px - b * HW_;

    float d = 0.0f, s2 = 0.0f;
#pragma unroll
    for (int sl = 0; sl < NSLICE; ++sl) {
        size_t idx = (size_t)(b * NSLICE + sl) * HW_ + p;
        d += wsd[idx];
        s2 += wss[idx];
    }
    float sv = d / fmaxf(sqrtf(s2), 1e-12f);
    float o = sv / TEMP_V;
    float* ob = out + (size_t)b * 2 * HW_;
    ob[p] = -o;
    ob[HW_ + p] = o;
}

extern "C" void kernel_launch(void* const* d_in, const int* in_sizes, int n_in,
                              void* d_out, int out_size, void* d_ws, size_t ws_size,
                              hipStream_t stream) {
    const float* support_feats = (const float*)d_in[0];
    const int* support_masks = (const int*)d_in[1];
    const float* query_feats = (const float*)d_in[2];
    const int* anchor_pos = (const int*)d_in[3];
    const int* anchor_sample = (const int*)d_in[4];
    const int* anchor_radius = (const int*)d_in[5];
    float* out = (float*)d_out;

    float* ws = (float*)d_ws;
    float* ws_partial = ws;                 // S*C = 1536
    float* ws_msum = ws_partial + S_ * C_;  // 64
    float* ws_proto = ws_msum + M_;         // M*C = 24576
    float* ws_v = ws_proto + M_ * C_;       // 384
    float* ws_fg = ws_v + C_;               // 1
    float* ws_dot = ws_fg + 1;              // B*NSLICE*HW = 294912
    float* ws_sq = ws_dot + B_ * NSLICE * HW_;  // 294912

    k_prep<<<NB_PREP, 256, 0, stream>>>(support_feats, support_masks, anchor_pos,
                                        anchor_sample, anchor_radius,
                                        ws_partial, ws_proto, ws_msum, ws_fg);
    k_finalize<<<1, 256, 0, stream>>>(ws_partial, ws_msum, ws_proto, ws_fg, ws_v);
    k_score1<<<NB_S1, 256, 0, stream>>>(query_feats, ws_v, ws_dot, ws_sq);
    k_score2<<<NB_S2, 256, 0, stream>>>(ws_dot, ws_sq, out);
}